// Round 3
// baseline (286.708 us; speedup 1.0000x reference)
//
#include <hip/hip_runtime.h>

// SCVC: out[n, g*OG+o, p, q] = C[g,o]*x[n,g,p]*y[n,g,q]
//                              + wA[g,o,0]*x[n,g,p-1] + wA[g,o,1]*x[n,g,p+1]
//                              + wB[g,o,0]*y[n,g,q-1] + wB[g,o,1]*y[n,g,q+1]
// Shapes: N=8, G=8, OG=16, DX=DY=256. Output fp32, 256 MiB -> store-BW-bound.
//
// Evidence so far (rocprof):
//  - Timed region = harness poison fill (1 GiB @ 6.6 TB/s, ~162 us, fixed)
//    + our kernel (~93 us = 2.9 TB/s).
//  - The fill reaches 6.6 TB/s at 10% occupancy (~3 waves/CU) -> peak store
//    BW needs no latency hiding; issue/occupancy explanations falsified.
//  - R4 (per-wave sequential 32 KB streams): only -5 us. Wave-level stream
//    shape is minor.
// R5 theory: the fill's win is its INSTANTANEOUS GLOBAL WRITE FOOTPRINT —
// a grid-stride loop keeps all resident waves' stores in one compact window
// that sweeps the buffer (self-synchronized by memory back-pressure); per
// DRAM channel that is sequential row access. Our per-block-region layout
// spreads 2048 concurrent streams over all 256 MiB -> row-buffer thrash.
// Fix: iteration-major sweep. At iter i, global wave w writes row
// r = i*8192 + w; all waves together write one contiguous 8 MiB slab per
// iteration. Block<->channel binding is gone, so LDS staging is replaced by
// per-iter wave-uniform loads (C/wA/wB/x, L1-hot) + one per-lane float4 of
// y, with q+-1 neighbors via intra-wave shuffles.
// Prediction: kernel 93 -> ~45-58 us, dur_us 255 -> ~208-220; WRITE_SIZE
// unchanged, FETCH_SIZE stays tiny. If unchanged -> try nontemporal stores.

#define N_  8
#define G_  8
#define OG_ 16
#define DX_ 256
#define DY_ 256

typedef float vfloat4 __attribute__((ext_vector_type(4)));

__global__ __launch_bounds__(256, 8) void scvc_kernel(
    const float* __restrict__ x,   // (N, G, DX)
    const float* __restrict__ y,   // (N, G, DY)
    const float* __restrict__ C,   // (G, OG)
    const float* __restrict__ wA,  // (G, OG, 2)
    const float* __restrict__ wB,  // (G, OG, 2)
    float* __restrict__ out)       // (N, G*OG, DX, DY)
{
    const int tid = threadIdx.x;
    const int qv  = tid & 63;                      // lane = float4 index in row
    const int wg  = (blockIdx.x << 2) | (tid >> 6); // global wave id 0..8191

    vfloat4* out4 = (vfloat4*)out;

#pragma unroll 2
    for (int i = 0; i < 32; ++i) {
        const int r  = (i << 13) + wg;   // global row id 0..262143 (sweeps)
        const int t  = r >> 8;           // channel 0..1023
        const int p  = r & 255;          // row within image
        const int ng = t >> 4;           // n*G + g, 0..63
        const int go = t & 127;          // g*OG + o, 0..127

        // Wave-uniform, same-address loads (L1-hot: C/wA/wB/x total < 80 KB).
        const float  co  = C[go];
        const float2 wa  = ((const float2*)wA)[go];
        const float2 wb  = ((const float2*)wB)[go];
        const float* xrow = x + ng * DX_;
        const float xv = xrow[p];
        const float xl = (p > 0)        ? xrow[p - 1] : 0.0f;
        const float xr = (p < DX_ - 1)  ? xrow[p + 1] : 0.0f;

        const float s  = co * xv;
        const float av = fmaf(wa.x, xl, wa.y * xr);

        // Per-lane y float4 (L1/L2-hot, 64 KB total); q+-1 via wave shuffles.
        const vfloat4 y4 = *(const vfloat4*)(y + ng * DY_ + (qv << 2));
        float ylm = __shfl_up(y4.w, 1);    // y[4*qv - 1]
        if (qv == 0) ylm = 0.0f;           // q = 0 boundary
        float yrp = __shfl_down(y4.x, 1);  // y[4*qv + 4]
        if (qv == 63) yrp = 0.0f;          // q = 255 boundary

        vfloat4 b4;
        b4.x = fmaf(wb.x, ylm,  wb.y * y4.y);
        b4.y = fmaf(wb.x, y4.x, wb.y * y4.z);
        b4.z = fmaf(wb.x, y4.y, wb.y * y4.w);
        b4.w = fmaf(wb.x, y4.z, wb.y * yrp);

        vfloat4 v;
        v.x = fmaf(s, y4.x, av + b4.x);
        v.y = fmaf(s, y4.y, av + b4.y);
        v.z = fmaf(s, y4.z, av + b4.z);
        v.w = fmaf(s, y4.w, av + b4.w);

        out4[(size_t)r * 64 + qv] = v;
    }
}

extern "C" void kernel_launch(void* const* d_in, const int* in_sizes, int n_in,
                              void* d_out, int out_size, void* d_ws, size_t ws_size,
                              hipStream_t stream) {
    const float* x  = (const float*)d_in[0];
    const float* y  = (const float*)d_in[1];
    const float* C  = (const float*)d_in[2];
    const float* wA = (const float*)d_in[3];
    const float* wB = (const float*)d_in[4];
    float* out = (float*)d_out;

    // 2048 blocks x 256 = 8192 waves; each wave writes one 1 KB row per
    // iteration; all waves sweep the 256 MiB output in 32 contiguous slabs.
    const int nblocks = 2048;
    scvc_kernel<<<nblocks, 256, 0, stream>>>(x, y, C, wA, wB, out);
}

// Round 4
// 259.983 us; speedup vs baseline: 1.1028x; 1.1028x over previous
//
#include <hip/hip_runtime.h>

// SCVC: out[n, g*OG+o, p, q] = C[g,o]*x[n,g,p]*y[n,g,q]
//                              + wA[g,o,0]*x[n,g,p-1] + wA[g,o,1]*x[n,g,p+1]
//                              + wB[g,o,0]*y[n,g,q-1] + wB[g,o,1]*y[n,g,q+1]
// Shapes: N=8, G=8, OG=16, DX=DY=256. Output fp32, 256 MiB -> store-BW-bound.
//
// Evidence ledger (rocprof):
//  - Timed region = harness poison fill (1 GiB @ 6.6 TB/s, ~162 us, fixed)
//    + kernel. Kernel times: R3 interleaved+LDS ~98 us; R4 contiguous
//    32-row wave runs ~93 us; R5 global slab-sweep + per-iter loads ~124 us
//    (REGRESSION -> sweep-as-implemented falsified).
//  - Fill hits 6.6 TB/s at ~10% occupancy (~800 waves) with STRIDED
//    per-wave streams -> per-wave shape irrelevant, occupancy unneeded,
//    per-CU store rate sufficient at 4 waves/CU.
// R6 theory: the remaining 10x difference vs fill is CONCURRENT WRITE
// STREAM COUNT: 2048 blocks / 8192 wave streams over 256 MiB (~32 streams
// per HBM pseudo-channel, row-buffer thrash) vs fill's ~800 (~3/channel).
// Single-variable test: keep R4's LDS-staged inner loop, shrink grid to
// 256 blocks (1/CU, 4 waves) ~ fill's concurrency. Each block processes 4
// whole channel-images sequentially (contiguous 256 KB region); each wave
// writes 64 contiguous rows/image. Issue headroom ~20x store budget.
// Prediction: kernel ~93 -> ~45-60 us (dur 255 -> ~210-225). If unchanged,
// stream-count falsified -> test nontemporal stores next.

#define N_  8
#define G_  8
#define OG_ 16
#define DX_ 256
#define DY_ 256

typedef float vfloat4 __attribute__((ext_vector_type(4)));

__global__ __launch_bounds__(256) void scvc_kernel(
    const float* __restrict__ x,   // (N, G, DX)
    const float* __restrict__ y,   // (N, G, DY)
    const float* __restrict__ C,   // (G, OG)
    const float* __restrict__ wA,  // (G, OG, 2)
    const float* __restrict__ wB,  // (G, OG, 2)
    float* __restrict__ out)       // (N, G*OG, DX, DY)
{
    __shared__ float sarr[DX_];   // C[g,o] * x[n,g,p]
    __shared__ float aarr[DX_];   // wA0*x[p-1] + wA1*x[p+1]
    __shared__ float ybuf[DY_];   // y[n,g,q]
    __shared__ float bbuf[DY_];   // wB0*y[q-1] + wB1*y[q+1]

    const int tid = threadIdx.x;
    const int qv  = tid & 63;      // lane = float4 index within a row
    const int wv  = tid >> 6;      // wave id 0..3 -> owns rows [wv*64, +64)

    // Each block handles 4 consecutive channel-images -> one contiguous
    // 1 MiB output region per block; 256 concurrent block streams total.
    for (int j = 0; j < 4; ++j) {
        const int t  = (blockIdx.x << 2) | j;  // channel 0..1023 (block-uniform)
        const int go = t & 127;                // g*OG + o
        const int ng = ((t >> 7) << 3) | (go >> 4);  // n*G + g

        __syncthreads();  // previous image's LDS reads done before overwrite
        {
            const float  co = C[go];
            const float2 wa = ((const float2*)wA)[go];
            const float2 wb = ((const float2*)wB)[go];
            const float* xrow = x + ng * DX_;
            const float* yrow = y + ng * DY_;

            float xv = xrow[tid];
            float xl = (tid > 0)       ? xrow[tid - 1] : 0.0f;
            float xr = (tid < DX_ - 1) ? xrow[tid + 1] : 0.0f;
            sarr[tid] = co * xv;
            aarr[tid] = fmaf(wa.x, xl, wa.y * xr);

            float yv = yrow[tid];
            float yl = (tid > 0)       ? yrow[tid - 1] : 0.0f;
            float yr = (tid < DY_ - 1) ? yrow[tid + 1] : 0.0f;
            ybuf[tid] = yv;
            bbuf[tid] = fmaf(wb.x, yl, wb.y * yr);
        }
        __syncthreads();

        const vfloat4 y4 = ((const vfloat4*)ybuf)[qv];
        const vfloat4 b4 = ((const vfloat4*)bbuf)[qv];

        float* obase = out + (size_t)t * (DX_ * DY_) + (size_t)(wv * 64) * DY_;

#pragma unroll 8
        for (int i = 0; i < 64; ++i) {
            const int p  = (wv << 6) + i;
            const float s  = sarr[p];
            const float av = aarr[p];
            vfloat4 v;
            v.x = fmaf(s, y4.x, av + b4.x);
            v.y = fmaf(s, y4.y, av + b4.y);
            v.z = fmaf(s, y4.z, av + b4.z);
            v.w = fmaf(s, y4.w, av + b4.w);
            ((vfloat4*)(obase + (size_t)i * DY_))[qv] = v;
        }
    }
}

extern "C" void kernel_launch(void* const* d_in, const int* in_sizes, int n_in,
                              void* d_out, int out_size, void* d_ws, size_t ws_size,
                              hipStream_t stream) {
    const float* x  = (const float*)d_in[0];
    const float* y  = (const float*)d_in[1];
    const float* C  = (const float*)d_in[2];
    const float* wA = (const float*)d_in[3];
    const float* wB = (const float*)d_in[4];
    float* out = (float*)d_out;

    const int nblocks = 256;  // 1 block/CU, ~fill-level write concurrency
    scvc_kernel<<<nblocks, 256, 0, stream>>>(x, y, C, wA, wB, out);
}